// Round 15
// baseline (469.311 us; speedup 1.0000x reference)
//
#include <hip/hip_runtime.h>
#include <hip/hip_bf16.h>

// Problem constants
#define BB   4
#define CC   64
#define SS   8
#define NN   (32*64*64)   // 131072
#define NH_  4
#define HD_  16
#define TA   128          // A2 n-tile
#define BPA  256          // A2 blocks per batch
#define NS1  512          // k_sim / k_feat blocks per batch (1 col/thread)
#define NTB2 4            // A2 tiles per block = (NN/TA)/BPA

typedef __attribute__((ext_vector_type(8))) short bf16x8;
typedef __attribute__((ext_vector_type(4))) float f32x4;

__device__ __forceinline__ float b2f(unsigned short h) {
    union { unsigned u; float f; } v; v.u = ((unsigned)h) << 16; return v.f;
}
__device__ __forceinline__ unsigned bfpack(float a, float b) {   // a->low, b->high
    union { float f; unsigned u; } x, y; x.f = a; y.f = b;
    unsigned ra = (x.u + 0x7FFFu + ((x.u >> 16) & 1u)) >> 16;
    unsigned rb = (y.u + 0x7FFFu + ((y.u >> 16) & 1u)) & 0xFFFF0000u;
    return ra | rb;
}

// ---------------------------------------------------------------------------
// Kernel P: one-time precompute.
//  blocks 0..15: M[cp][c] = sum_o s2fw[o][cp]*fw[o][c]
//  block  16   : g0[c], hv[cp], h0
//  block  17   : snT[c][s] = slot_init[c][s]/||slot_s||  (c-major 64x8)
// ---------------------------------------------------------------------------
__global__ __launch_bounds__(256) void k_precomp(
    const float* __restrict__ slot_init,
    const float* __restrict__ s2fw, const float* __restrict__ s2fb,
    const float* __restrict__ fw, const float* __restrict__ fb,
    float* __restrict__ M, float* __restrict__ g0v,
    float* __restrict__ hv, float* __restrict__ h0,
    float* __restrict__ snT_ws)
{
    const int tid = threadIdx.x;
    if (blockIdx.x < 16) {
        const int cp = blockIdx.x*4 + (tid >> 6);
        const int c  = tid & 63;
        float acc = 0.f;
        #pragma unroll 8
        for (int o = 0; o < CC; ++o)
            acc += s2fw[o*CC + cp] * fw[o*CC + c];
        M[cp*CC + c] = acc;
    } else if (blockIdx.x == 16) {
        if (tid < 64) {
            float acc = 0.f;
            #pragma unroll 8
            for (int o = 0; o < CC; ++o) acc += s2fb[o] * fw[o*CC + tid];
            g0v[tid] = acc;
        } else if (tid < 128) {
            const int cp = tid - 64;
            float acc = 0.f;
            #pragma unroll 8
            for (int o = 0; o < CC; ++o) acc += s2fw[o*CC + cp] * fb[o];
            hv[cp] = acc;
        } else if (tid == 128) {
            float acc = 0.f;
            for (int o = 0; o < CC; ++o) acc += s2fb[o] * fb[o];
            *h0 = acc;
        }
    } else {
        __shared__ float nrm[SS];
        if (tid < 64) {
            const int s = tid & 7, ch = tid >> 3;
            float p = 0.f;
            #pragma unroll
            for (int j = 0; j < 8; ++j) {
                float v = slot_init[(ch*8 + j)*SS + s];
                p += v*v;
            }
            p += __shfl_xor(p, 8); p += __shfl_xor(p, 16); p += __shfl_xor(p, 32);
            if (tid < 8) nrm[s] = fmaxf(sqrtf(p), 1e-12f);
        }
        __syncthreads();
        for (int i = tid; i < SS*CC; i += 256) {
            const int c = i >> 3, s = i & 7;          // c-major output
            snT_ws[i] = slot_init[c*SS + s] / nrm[s];
        }
    }
}

// ---------------------------------------------------------------------------
// Kernel A1 v3: streaming sim/exp. ONE column/thread (100% occupancy).
// Scalar fp32 reads (fully coalesced). bf16 writes via adjacent-lane pack:
// px = shfl_xor(xv,1); even lanes store bfpack(xv,px) -> 4B granule,
// 128 contiguous bytes per wave, full coverage.
// ---------------------------------------------------------------------------
__global__ __launch_bounds__(256) void k_sim(
    const float* __restrict__ x, const float* __restrict__ snT_ws,
    unsigned short* __restrict__ xb16, unsigned short* __restrict__ ebf,
    float* __restrict__ sume_part)
{
    __shared__ float snT[CC*SS];       // [c][s]
    __shared__ float red[SS*256];

    const int tid  = threadIdx.x;
    const int b    = blockIdx.x >> 9;
    const int blk1 = blockIdx.x & 511;
    const int n    = (blk1 << 8) + tid;

    if (tid < 128) *(float4*)&snT[tid*4] = *(const float4*)&snT_ws[tid*4];
    __syncthreads();

    const float* xcol = x + (size_t)b*CC*NN + n;
    unsigned short* xo = xb16 + (size_t)b*CC*NN + n;
    const bool wlane = ((tid & 1) == 0);

    float ss = 0.f;
    float a[SS];
    #pragma unroll
    for (int s = 0; s < SS; ++s) a[s] = 0.f;

    #pragma unroll
    for (int c = 0; c < CC; ++c) {
        const float xv = xcol[(size_t)c*NN];
        const float px = __shfl_xor(xv, 1);
        if (wlane) *(unsigned*)(xo + (size_t)c*NN) = bfpack(xv, px);
        ss += xv*xv;
        const float4 g0 = *(const float4*)&snT[c*8];
        const float4 g1 = *(const float4*)&snT[c*8 + 4];
        a[0] += g0.x*xv; a[1] += g0.y*xv; a[2] += g0.z*xv; a[3] += g0.w*xv;
        a[4] += g1.x*xv; a[5] += g1.y*xv; a[6] += g1.z*xv; a[7] += g1.w*xv;
    }

    const float invn = 1.f / fmaxf(sqrtf(ss), 1e-12f);
    unsigned short* eo = ebf + (size_t)b*SS*NN + n;
    float esum[SS];
    #pragma unroll
    for (int s = 0; s < SS; ++s) {
        const float e = __expf(a[s] * invn);
        const float pe = __shfl_xor(e, 1);
        if (wlane) *(unsigned*)(eo + (size_t)s*NN) = bfpack(e, pe);
        esum[s] = e;
    }

    // L block-partials
    #pragma unroll
    for (int s = 0; s < SS; ++s) red[s*256 + tid] = esum[s];
    __syncthreads();
    {
        const int s = tid >> 5, j = tid & 31;
        float v = 0.f;
        #pragma unroll
        for (int k = 0; k < 8; ++k) v += red[s*256 + j*8 + k];
        v += __shfl_xor(v, 1); v += __shfl_xor(v, 2); v += __shfl_xor(v, 4);
        v += __shfl_xor(v, 8); v += __shfl_xor(v, 16);
        if (j == 0) sume_part[(size_t)(b*NS1 + blk1)*SS + s] = v;
    }
}

// ---------------------------------------------------------------------------
// Kernel A2: pure bf16 GEMM  U^T(c,s) += x16(c,n) @ e^T(n,s), MFMA,
// gload_lds double-buffered, counted pipeline. 36 KB LDS -> 4 blocks/CU.
// 16B-slot XOR swizzle (^row&7): linear LDS dest + pre-swizzled global src.
// ---------------------------------------------------------------------------
__global__ __launch_bounds__(256) void k_gemm_u(
    const unsigned short* __restrict__ xb16, const unsigned short* __restrict__ ebf,
    float* __restrict__ U_part)
{
    __shared__ short xt[2][CC*TA];     // 2 x 16 KB
    __shared__ short et[2][SS*TA];     // 2 x 2 KB
    __shared__ short etz[TA];          // zero row (B rows 8..15)

    const int tid = threadIdx.x;
    const int b   = blockIdx.x / BPA;
    const int blk = blockIdx.x % BPA;
    const int lane = tid & 63, wv = tid >> 6;

    if (tid < 64) ((int*)etz)[tid] = 0;

    const unsigned short* xg = xb16 + (size_t)b*CC*NN;
    const unsigned short* eg = ebf  + (size_t)b*SS*NN;

    f32x4 accU = {0.f, 0.f, 0.f, 0.f};

    #define STG(buf, t)                                                        \
    {                                                                          \
        const int n0_ = (t) * TA;                                              \
        _Pragma("unroll")                                                      \
        for (int k = 0; k < 4; ++k) {                                          \
            const int c_ = wv*16 + k*4 + (lane >> 4);                          \
            const int j_ = (lane & 15) ^ (c_ & 7);                             \
            const unsigned short* src_ = xg + (size_t)c_*NN + n0_ + j_*8;      \
            short* dst_ = &xt[buf][(wv*16 + k*4)*TA];                          \
            __builtin_amdgcn_global_load_lds(                                  \
                (const __attribute__((address_space(1))) void*)src_,           \
                (__attribute__((address_space(3))) void*)dst_, 16, 0, 0);      \
        }                                                                      \
        if (wv == 0) {                                                         \
            _Pragma("unroll")                                                  \
            for (int k = 0; k < 2; ++k) {                                      \
                const int s_ = k*4 + (lane >> 4);                              \
                const int j_ = (lane & 15) ^ (s_ & 7);                         \
                const unsigned short* src_ = eg + (size_t)s_*NN + n0_ + j_*8;  \
                short* dst_ = &et[buf][k*4*TA];                                \
                __builtin_amdgcn_global_load_lds(                              \
                    (const __attribute__((address_space(1))) void*)src_,       \
                    (__attribute__((address_space(3))) void*)dst_, 16, 0, 0);  \
            }                                                                  \
        }                                                                      \
    }

    int cur = 0;
    STG(0, blk);
    asm volatile("s_waitcnt vmcnt(0)" ::: "memory");
    __syncthreads();

    for (int tt = 0; tt < NTB2; ++tt) {
        if (tt + 1 < NTB2) STG(cur ^ 1, blk + (tt+1)*BPA);

        // MFMA: wave wv owns c-tile [16wv, 16wv+16), K = 128 -> 4 steps
        {
            const int ca  = (wv << 4) + (lane & 15);
            const int rbq = lane & 15;
            const int p   = lane >> 4;
            const short* brow = (rbq < 8) ? &et[cur][rbq*TA] : etz;
            const int bsw = (rbq < 8) ? (rbq & 7) : 0;
            #pragma unroll
            for (int kk = 0; kk < 4; ++kk) {
                const int sl = kk*4 + p;
                const bf16x8 af  = *(const bf16x8*)&xt[cur][ca*TA + ((sl ^ (ca & 7)) << 3)];
                const bf16x8 bfr = *(const bf16x8*)&brow[(sl ^ bsw) << 3];
                accU = __builtin_amdgcn_mfma_f32_16x16x32_bf16(af, bfr, accU, 0, 0, 0);
            }
        }
        asm volatile("s_waitcnt vmcnt(0)" ::: "memory");
        __syncthreads();
        cur ^= 1;
    }
    #undef STG

    // write U^T partials: D col = lane&15 = s, row = (lane>>4)*4 + reg = c-off
    {
        const size_t base = ((size_t)(b*BPA + blk) * SS) * CC;
        if ((lane & 15) < SS) {
            const int s  = lane & 15;
            const int c0 = (wv << 4) + ((lane >> 4) << 2);
            #pragma unroll
            for (int r = 0; r < 4; ++r)
                U_part[base + s*CC + c0 + r] = accU[r];
        }
    }
}

// ---------------------------------------------------------------------------
// Kernel R: parallel reduce of partials -> upd[b,s,c] = U/L directly.
// ---------------------------------------------------------------------------
__global__ __launch_bounds__(256) void k_reduce2(
    const float* __restrict__ U_part, const float* __restrict__ sume_part,
    float* __restrict__ upd_g, int nU, int nL)
{
    __shared__ float part[4][64];
    __shared__ float lbuf[256];
    __shared__ float Lsh;
    const int tid = threadIdx.x;
    const int b = blockIdx.x >> 3, s = blockIdx.x & 7;
    const int c = tid & 63, kc = tid >> 6;
    const int cnt = nU >> 2;

    float lv = 0.f;
    for (int k = tid; k < nL; k += 256)
        lv += sume_part[(size_t)(b*nL + k)*SS + s];
    lbuf[tid] = lv;

    float acc[8];
    #pragma unroll
    for (int j = 0; j < 8; ++j) acc[j] = 0.f;
    const float* base = U_part + ((size_t)(b*nU + kc*cnt)*SS + s)*CC + c;
    for (int k = 0; k < cnt; k += 8) {
        #pragma unroll
        for (int j = 0; j < 8; ++j)
            acc[j] += base[(size_t)(k + j) * SS * CC];
    }
    part[kc][c] = ((acc[0]+acc[1]) + (acc[2]+acc[3]))
                + ((acc[4]+acc[5]) + (acc[6]+acc[7]));
    __syncthreads();

    if (tid < 128) lbuf[tid] += lbuf[tid + 128];
    __syncthreads();
    if (tid < 64) {
        float v = lbuf[tid] + lbuf[tid + 64];
        v += __shfl_xor(v, 1); v += __shfl_xor(v, 2); v += __shfl_xor(v, 4);
        v += __shfl_xor(v, 8); v += __shfl_xor(v, 16); v += __shfl_xor(v, 32);
        if (tid == 0) Lsh = v;
    }
    __syncthreads();

    if (tid < 64) {
        float u = part[0][c] + part[1][c] + part[2][c] + part[3][c];
        upd_g[((size_t)b*SS + s)*CC + c] = u / Lsh;
    }
}

// ---------------------------------------------------------------------------
// Kernel B: slot pipeline. 4 blocks (one per batch), 256 threads.
// ---------------------------------------------------------------------------
__global__ __launch_bounds__(256) void k_slots_small(
    const float* __restrict__ upd_g,
    const float* __restrict__ spw, const float* __restrict__ spb,
    const float* __restrict__ lng, const float* __restrict__ lnb,
    const float* __restrict__ ipw, const float* __restrict__ ipb,
    const float* __restrict__ opw, const float* __restrict__ opb,
    const float* __restrict__ M, const float* __restrict__ g0v,
    const float* __restrict__ hv, const float* __restrict__ h0,
    float* __restrict__ st_out, float* __restrict__ g_out, float* __restrict__ h_out)
{
    __shared__ float upd[SS*CC];
    __shared__ float st [SS*CC];
    __shared__ float snb[SS*CC];
    __shared__ float qkv[SS*3*CC];
    __shared__ float ot [SS*CC];

    const int tid  = threadIdx.x;
    const int b    = blockIdx.x;
    const int c    = tid & 63;
    const int quad = tid >> 6;
    const int r0 = quad*2, r1 = r0 + 1;
    float wreg[CC];

    #pragma unroll
    for (int i = 0; i < 16; ++i)
        *(float4*)&wreg[i*4] = *(const float4*)(spw + c*CC + i*4);
    upd[r0*CC + c] = upd_g[(b*SS + r0)*CC + c];
    upd[r1*CC + c] = upd_g[(b*SS + r1)*CC + c];
    __syncthreads();

    // P1: slot_proj
    {
        const float bias = spb[c];
        float a0 = bias, a1 = bias;
        #pragma unroll
        for (int i = 0; i < 16; ++i) {
            float4 u0 = *(const float4*)&upd[r0*CC + i*4];
            float4 u1 = *(const float4*)&upd[r1*CC + i*4];
            a0 += u0.x*wreg[i*4+0] + u0.y*wreg[i*4+1] + u0.z*wreg[i*4+2] + u0.w*wreg[i*4+3];
            a1 += u1.x*wreg[i*4+0] + u1.y*wreg[i*4+1] + u1.z*wreg[i*4+2] + u1.w*wreg[i*4+3];
        }
        st[r0*CC + c] = a0;
        st[r1*CC + c] = a1;
    }
    __syncthreads();

    // P2: LayerNorm (32 threads per row)
    {
        const int row = tid >> 5, l = tid & 31;
        float v0 = st[row*CC + l], v1 = st[row*CC + l + 32];
        float sum = v0 + v1;
        sum += __shfl_xor(sum, 1); sum += __shfl_xor(sum, 2); sum += __shfl_xor(sum, 4);
        sum += __shfl_xor(sum, 8); sum += __shfl_xor(sum, 16);
        const float mu = sum * (1.f/64.f);
        const float d0 = v0 - mu, d1 = v1 - mu;
        float vs = d0*d0 + d1*d1;
        vs += __shfl_xor(vs, 1); vs += __shfl_xor(vs, 2); vs += __shfl_xor(vs, 4);
        vs += __shfl_xor(vs, 8); vs += __shfl_xor(vs, 16);
        const float rstd = rsqrtf(vs * (1.f/64.f) + 1e-5f);
        snb[row*CC + l]      = d0 * rstd * lng[l]      + lnb[l];
        snb[row*CC + l + 32] = d1 * rstd * lng[l + 32] + lnb[l + 32];
    }
    __syncthreads();

    // P3: qkv
    for (int m = 0; m < 3; ++m) {
        #pragma unroll
        for (int i = 0; i < 16; ++i)
            *(float4*)&wreg[i*4] = *(const float4*)(ipw + (size_t)(m*CC + c)*CC + i*4);
        const float bias = ipb[m*CC + c];
        float a0 = bias, a1 = bias;
        #pragma unroll
        for (int i = 0; i < 16; ++i) {
            float4 u0 = *(const float4*)&snb[r0*CC + i*4];
            float4 u1 = *(const float4*)&snb[r1*CC + i*4];
            a0 += u0.x*wreg[i*4+0] + u0.y*wreg[i*4+1] + u0.z*wreg[i*4+2] + u0.w*wreg[i*4+3];
            a1 += u1.x*wreg[i*4+0] + u1.y*wreg[i*4+1] + u1.z*wreg[i*4+2] + u1.w*wreg[i*4+3];
        }
        qkv[r0*3*CC + m*CC + c] = a0;
        qkv[r1*3*CC + m*CC + c] = a1;
    }
    __syncthreads();

    // P4: MHSA, 32 threads = (h,q)
    if (tid < NH_*SS) {
        const int h = tid >> 3, q = tid & 7;
        float qreg[HD_];
        #pragma unroll
        for (int i = 0; i < 4; ++i)
            *(float4*)&qreg[i*4] = *(const float4*)&qkv[q*3*CC + h*HD_ + i*4];
        float srow[SS];
        float mx = -1e30f;
        #pragma unroll
        for (int k = 0; k < SS; ++k) {
            float acc = 0.f;
            #pragma unroll
            for (int d = 0; d < HD_; ++d)
                acc += qreg[d] * qkv[k*3*CC + CC + h*HD_ + d];
            srow[k] = acc * 0.25f;
            mx = fmaxf(mx, srow[k]);
        }
        float l = 0.f;
        #pragma unroll
        for (int k = 0; k < SS; ++k) { srow[k] = __expf(srow[k] - mx); l += srow[k]; }
        const float inv = 1.f / l;
        float oreg[HD_];
        #pragma unroll
        for (int d = 0; d < HD_; ++d) oreg[d] = 0.f;
        #pragma unroll
        for (int k = 0; k < SS; ++k) {
            #pragma unroll
            for (int d = 0; d < HD_; ++d)
                oreg[d] += srow[k] * qkv[k*3*CC + 2*CC + h*HD_ + d];
        }
        #pragma unroll
        for (int d = 0; d < HD_; ++d)
            ot[q*CC + h*HD_ + d] = oreg[d] * inv;
    }
    __syncthreads();

    // P5: out_proj + residual
    #pragma unroll
    for (int i = 0; i < 16; ++i)
        *(float4*)&wreg[i*4] = *(const float4*)(opw + c*CC + i*4);
    {
        const float bias = opb[c];
        float a0 = bias, a1 = bias;
        #pragma unroll
        for (int i = 0; i < 16; ++i) {
            float4 u0 = *(const float4*)&ot[r0*CC + i*4];
            float4 u1 = *(const float4*)&ot[r1*CC + i*4];
            a0 += u0.x*wreg[i*4+0] + u0.y*wreg[i*4+1] + u0.z*wreg[i*4+2] + u0.w*wreg[i*4+3];
            a1 += u1.x*wreg[i*4+0] + u1.y*wreg[i*4+1] + u1.z*wreg[i*4+2] + u1.w*wreg[i*4+3];
        }
        st[r0*CC + c] += a0;
        st[r1*CC + c] += a1;
    }
    __syncthreads();

    // P6: g = st @ M + g0 ; emit st ; h = st.hv + h0
    #pragma unroll 8
    for (int cp = 0; cp < CC; ++cp) wreg[cp] = M[cp*CC + c];
    {
        const float g0 = g0v[c];
        float a0 = g0, a1 = g0;
        #pragma unroll
        for (int i = 0; i < 16; ++i) {
            float4 s0 = *(const float4*)&st[r0*CC + i*4];
            float4 s1 = *(const float4*)&st[r1*CC + i*4];
            a0 += s0.x*wreg[i*4+0] + s0.y*wreg[i*4+1] + s0.z*wreg[i*4+2] + s0.w*wreg[i*4+3];
            a1 += s1.x*wreg[i*4+0] + s1.y*wreg[i*4+1] + s1.z*wreg[i*4+2] + s1.w*wreg[i*4+3];
        }
        g_out[(b*SS + r0)*CC + c] = a0;
        g_out[(b*SS + r1)*CC + c] = a1;
        st_out[(b*SS + r0)*CC + c] = st[r0*CC + c];
        st_out[(b*SS + r1)*CC + c] = st[r1*CC + c];
    }
    {
        const int row = tid >> 5, l = tid & 31;
        float pv = st[row*CC + l]*hv[l] + st[row*CC + l + 32]*hv[l + 32];
        pv += __shfl_xor(pv, 1); pv += __shfl_xor(pv, 2); pv += __shfl_xor(pv, 4);
        pv += __shfl_xor(pv, 8); pv += __shfl_xor(pv, 16);
        if (l == 0) h_out[b*SS + row] = pv + *h0;
    }
}

// ---------------------------------------------------------------------------
// Kernel C v3: stage-3 fused pass. ONE column/thread, reads xb16 (L3-hot)
// via duplicate-address dword loads (lane n and n+1 load the same uint at
// n&~1, extract parity half) -> 4B coalesced, no 2-byte accesses.
// xc[64] persistent (~90 VGPR); NT fp32 stores.
// ---------------------------------------------------------------------------
__global__ __launch_bounds__(256) void k_feat(
    const unsigned short* __restrict__ xb16,
    const float* __restrict__ st_g, const float* __restrict__ g_g,
    const float* __restrict__ h_g,
    float* __restrict__ out)
{
    __shared__ float stS[SS*CC];
    __shared__ float gS [SS*CC];
    __shared__ float hS [SS];

    const int tid = threadIdx.x;
    const int b  = blockIdx.x >> 9;
    const int n  = ((blockIdx.x & 511) << 8) + tid;

    for (int i = tid; i < SS*CC; i += 256) {
        stS[i] = st_g[b*SS*CC + i];
        gS[i]  = g_g [b*SS*CC + i];
    }
    if (tid < SS) hS[tid] = h_g[b*SS + tid];
    __syncthreads();

    const unsigned short* xbh = xb16 + (size_t)b*CC*NN + (n & ~1);
    const bool hi = (n & 1);

    float xc[CC];
    float a[SS];
    #pragma unroll
    for (int s = 0; s < SS; ++s) a[s] = hS[s];

    #pragma unroll
    for (int c4 = 0; c4 < CC/4; ++c4) {
        #pragma unroll
        for (int j = 0; j < 4; ++j) {
            const unsigned u = *(const unsigned*)(xbh + (size_t)(c4*4 + j)*NN);
            xc[c4*4 + j] = hi ? b2f((unsigned short)(u >> 16))
                              : b2f((unsigned short)(u & 0xFFFFu));
        }
        #pragma unroll
        for (int s = 0; s < SS; ++s) {
            const float4 g4 = *(const float4*)(&gS[s*CC + c4*4]);
            a[s] += g4.x*xc[c4*4+0] + g4.y*xc[c4*4+1]
                  + g4.z*xc[c4*4+2] + g4.w*xc[c4*4+3];
        }
    }

    // softmax over slots
    float m = a[0];
    #pragma unroll
    for (int s = 1; s < SS; ++s) m = fmaxf(m, a[s]);
    float l = 0.f;
    #pragma unroll
    for (int s = 0; s < SS; ++s) { a[s] = __expf(a[s] - m); l += a[s]; }
    const float inv = 1.f / l;
    #pragma unroll
    for (int s = 0; s < SS; ++s) a[s] *= inv;

    // slot-mix + residual; nontemporal stores
    float* ob = out + (size_t)b * CC * NN + n;
    #pragma unroll
    for (int c4 = 0; c4 < CC/4; ++c4) {
        float o0 = 0.f, o1 = 0.f, o2 = 0.f, o3 = 0.f;
        #pragma unroll
        for (int s = 0; s < SS; ++s) {
            const float4 s4 = *(const float4*)(&stS[s*CC + c4*4]);
            o0 += s4.x * a[s]; o1 += s4.y * a[s];
            o2 += s4.z * a[s]; o3 += s4.w * a[s];
        }
        __builtin_nontemporal_store(o0 + xc[c4*4+0], ob + (size_t)(c4*4+0) * NN);
        __builtin_nontemporal_store(o1 + xc[c4*4+1], ob + (size_t)(c4*4+1) * NN);
        __builtin_nontemporal_store(o2 + xc[c4*4+2], ob + (size_t)(c4*4+2) * NN);
        __builtin_nontemporal_store(o3 + xc[c4*4+3], ob + (size_t)(c4*4+3) * NN);
    }
}

// ---------------------------------------------------------------------------
extern "C" void kernel_launch(void* const* d_in, const int* in_sizes, int n_in,
                              void* d_out, int out_size, void* d_ws, size_t ws_size,
                              hipStream_t stream) {
    const float* x         = (const float*)d_in[0];
    const float* slot_init = (const float*)d_in[1];
    const float* spw       = (const float*)d_in[2];
    const float* spb       = (const float*)d_in[3];
    const float* lng       = (const float*)d_in[4];
    const float* lnb       = (const float*)d_in[5];
    const float* ipw       = (const float*)d_in[6];
    const float* ipb       = (const float*)d_in[7];
    const float* opw       = (const float*)d_in[8];
    const float* opb       = (const float*)d_in[9];
    const float* fw        = (const float*)d_in[10];
    const float* fb        = (const float*)d_in[11];
    const float* s2fw      = (const float*)d_in[12];
    const float* s2fb      = (const float*)d_in[13];
    float* out = (float*)d_out;

    // workspace layout (floats; bf16 regions carved at the end)
    float* w         = (float*)d_ws;
    float* U_part    = w;                                  // 4*256*8*64 = 524288
    float* sume_part = U_part + (size_t)BB*BPA*SS*CC;      // 4*512*8 = 16384
    float* upd_g     = sume_part + (size_t)BB*NS1*SS;      // 2048
    float* Mm        = upd_g + 2048;                       // 4096
    float* g0v       = Mm + 4096;                          // 64
    float* hv        = g0v + 64;                           // 64
    float* h0        = hv + 64;                            // 64 (1 used)
    float* snT_ws    = h0 + 64;                            // 512 (1024 reserved)
    float* st_out    = snT_ws + 1024;                      // 2048
    float* g_out     = st_out + 2048;                      // 2048
    float* h_out     = g_out + 2048;                       // 32 (64 reserved)
    unsigned short* xb16 = (unsigned short*)(h_out + 64);  // BB*CC*NN bf16 = 64 MiB
    unsigned short* ebf  = xb16 + (size_t)BB*CC*NN;        // BB*SS*NN bf16 = 8 MiB

    k_precomp<<<18, 256, 0, stream>>>(slot_init, s2fw, s2fb, fw, fb,
                                      Mm, g0v, hv, h0, snT_ws);
    k_sim<<<BB * NS1, 256, 0, stream>>>(x, snT_ws, xb16, ebf, sume_part);
    k_gemm_u<<<BB * BPA, 256, 0, stream>>>(xb16, ebf, U_part);
    k_reduce2<<<BB * SS, 256, 0, stream>>>(U_part, sume_part, upd_g, BPA, NS1);
    k_slots_small<<<BB, 256, 0, stream>>>(upd_g, spw, spb, lng, lnb,
                                          ipw, ipb, opw, opb, Mm, g0v, hv, h0,
                                          st_out, g_out, h_out);
    k_feat<<<BB * NS1, 256, 0, stream>>>(xb16, st_out, g_out, h_out, out);
}

// Round 16
// 124.939 us; speedup vs baseline: 3.7563x; 3.7563x over previous
//
#include <hip/hip_runtime.h>
#include <hip/hip_bf16.h>

// Problem constants
#define BB   4
#define CC   64
#define SS   8
#define NN   (32*64*64)   // 131072
#define NH_  4
#define HD_  16
#define TA   128          // n-tile for stage-1 kernel (fp32 LDS, dbuf)
#define BPA  128          // blocks per batch in stage-1 kernel
#define NTB  8            // tiles per block = (NN/TA)/BPA

typedef __attribute__((ext_vector_type(8))) short bf16x8;
typedef __attribute__((ext_vector_type(4))) float f32x4;

__device__ __forceinline__ unsigned short f2b(float f) {
    union { float f; unsigned u; } v; v.f = f;
    unsigned r = v.u + 0x7FFFu + ((v.u >> 16) & 1u);
    return (unsigned short)(r >> 16);
}
__device__ __forceinline__ unsigned bfpack(float a, float b) {   // a->low, b->high
    union { float f; unsigned u; } x, y; x.f = a; y.f = b;
    unsigned ra = (x.u + 0x7FFFu + ((x.u >> 16) & 1u)) >> 16;
    unsigned rb = (y.u + 0x7FFFu + ((y.u >> 16) & 1u)) & 0xFFFF0000u;
    return ra | rb;
}

// ---------------------------------------------------------------------------
// Kernel P: one-time precompute.
//  blocks 0..15: M[cp][c] = sum_o s2fw[o][cp]*fw[o][c]
//  block  16   : g0[c], hv[cp], h0
//  block  17   : snT[c][s] = slot_init[c][s]/||slot_s||  (c-major 64x8)
// ---------------------------------------------------------------------------
__global__ __launch_bounds__(256) void k_precomp(
    const float* __restrict__ slot_init,
    const float* __restrict__ s2fw, const float* __restrict__ s2fb,
    const float* __restrict__ fw, const float* __restrict__ fb,
    float* __restrict__ M, float* __restrict__ g0v,
    float* __restrict__ hv, float* __restrict__ h0,
    float* __restrict__ snT_ws)
{
    const int tid = threadIdx.x;
    if (blockIdx.x < 16) {
        const int cp = blockIdx.x*4 + (tid >> 6);
        const int c  = tid & 63;
        float acc = 0.f;
        #pragma unroll 8
        for (int o = 0; o < CC; ++o)
            acc += s2fw[o*CC + cp] * fw[o*CC + c];
        M[cp*CC + c] = acc;
    } else if (blockIdx.x == 16) {
        if (tid < 64) {
            float acc = 0.f;
            #pragma unroll 8
            for (int o = 0; o < CC; ++o) acc += s2fb[o] * fw[o*CC + tid];
            g0v[tid] = acc;
        } else if (tid < 128) {
            const int cp = tid - 64;
            float acc = 0.f;
            #pragma unroll 8
            for (int o = 0; o < CC; ++o) acc += s2fw[o*CC + cp] * fb[o];
            hv[cp] = acc;
        } else if (tid == 128) {
            float acc = 0.f;
            for (int o = 0; o < CC; ++o) acc += s2fb[o] * fb[o];
            *h0 = acc;
        }
    } else {
        __shared__ float nrm[SS];
        if (tid < 64) {
            const int s = tid & 7, ch = tid >> 3;
            float p = 0.f;
            #pragma unroll
            for (int j = 0; j < 8; ++j) {
                float v = slot_init[(ch*8 + j)*SS + s];
                p += v*v;
            }
            p += __shfl_xor(p, 8); p += __shfl_xor(p, 16); p += __shfl_xor(p, 32);
            if (tid < 8) nrm[s] = fmaxf(sqrtf(p), 1e-12f);
        }
        __syncthreads();
        for (int i = tid; i < SS*CC; i += 256) {
            const int c = i >> 3, s = i & 7;          // c-major output
            snT_ws[i] = slot_init[c*SS + s] / nrm[s];
        }
    }
}

// ---------------------------------------------------------------------------
// Kernel A: stage-1 pass over x.  global_load_lds + double-buffered fp32 LDS
// tile + counted-wait 2-phase pipeline.
//   per tile: STAGE(next) -> dot partials (LDS b32, 2-way max) -> exchange ->
//             exp/et -> MFMA (A-frag fp32->bf16 in-reg) -> vmcnt(0)+barrier.
// LDS dest is linear (gload_lds constraint); the 16B-slot XOR swizzle
// (^ c&7) is applied on the per-lane GLOBAL source address and on every read.
// 512 blocks = exactly 2/CU, 8 tiles each.  (R9's proven 127 us config.)
// ---------------------------------------------------------------------------
__global__ __launch_bounds__(256) void k_slots_attn(
    const float* __restrict__ x, const float* __restrict__ snT_ws,
    float* __restrict__ U_part, float* __restrict__ sume_part)
{
    __shared__ float xlds[2][CC * TA];   // 2 x 32 KB fp32
    __shared__ short et[9 * TA];         // 2.25 KB bf16 (row 8 = zeros)
    __shared__ float snT[CC * SS];       // 2 KB [c][s]
    __shared__ float red[2 * 9 * TA];    // 9 KB partial exchange [half][9][col]

    const int tid = threadIdx.x;
    const int b   = blockIdx.x / BPA;
    const int blk = blockIdx.x % BPA;
    const int lane = tid & 63, wv = tid >> 6;
    const int col = tid & 127, half = tid >> 7;

    // prologue: zero et row 8; copy snT (visible after first barrier)
    if (tid < 64) ((int*)&et[8*TA])[tid] = 0;
    if (tid < 128) *(float4*)&snT[tid*4] = *(const float4*)&snT_ws[tid*4];

    const float* xb = x + (size_t)b * CC * NN;

    f32x4 accU = {0.f, 0.f, 0.f, 0.f};
    float accS[SS];
    #pragma unroll
    for (int s = 0; s < SS; ++s) accS[s] = 0.f;

    // ---- async stage of tile t into buffer buf (linear dest, pre-swz src) --
    #define STAGE(buf, t)                                                      \
    {                                                                          \
        const int n0_ = (t) * TA;                                              \
        _Pragma("unroll")                                                      \
        for (int k = 0; k < 8; ++k) {                                          \
            const int c_  = (wv*8 + k)*2 + (lane >> 5);                        \
            const int jg_ = (lane & 31) ^ (c_ & 7);                            \
            const float* src_ = xb + (size_t)c_*NN + n0_ + jg_*4;              \
            float* dst_ = &xlds[buf][(wv*8 + k)*256];                          \
            __builtin_amdgcn_global_load_lds(                                  \
                (const __attribute__((address_space(1))) void*)src_,           \
                (__attribute__((address_space(3))) void*)dst_, 16, 0, 0);      \
        }                                                                      \
    }

    int cur = 0;
    STAGE(0, blk);
    asm volatile("s_waitcnt vmcnt(0)" ::: "memory");
    __syncthreads();

    for (int tt = 0; tt < NTB; ++tt) {
        if (tt + 1 < NTB) STAGE(cur ^ 1, blk + (tt+1)*BPA);

        // ---- dot partials: thread = (col, c-half), swizzled b32 reads ----
        {
            const float* xl = &xlds[cur][0];
            float ss = 0.f;
            float a[SS];
            #pragma unroll
            for (int s = 0; s < SS; ++s) a[s] = 0.f;
            #pragma unroll
            for (int ci = 0; ci < 32; ++ci) {
                const int c = half*32 + ci;
                const float xv = xl[c*TA + (((col>>2) ^ (c&7)) << 2) + (col&3)];
                ss += xv * xv;
                const float4 g0 = *(const float4*)&snT[c*8];
                const float4 g1 = *(const float4*)&snT[c*8 + 4];
                a[0] += g0.x*xv; a[1] += g0.y*xv; a[2] += g0.z*xv; a[3] += g0.w*xv;
                a[4] += g1.x*xv; a[5] += g1.y*xv; a[6] += g1.z*xv; a[7] += g1.w*xv;
            }
            red[(half*9 + 8)*TA + col] = ss;
            #pragma unroll
            for (int s = 0; s < SS; ++s) red[(half*9 + s)*TA + col] = a[s];
        }
        __syncthreads();

        // ---- finalize: 128 threads, one column each ----
        if (tid < TA) {
            const float ss = red[8*TA + tid] + red[(9+8)*TA + tid];
            const float invn = 1.f / fmaxf(sqrtf(ss), 1e-12f);
            #pragma unroll
            for (int s = 0; s < SS; ++s) {
                const float av = red[s*TA + tid] + red[(9+s)*TA + tid];
                const float e = __expf(av * invn);
                accS[s] += e;
                et[s*TA + ((((tid>>3) ^ s) << 3) | (tid & 7))] = (short)f2b(e);
            }
        }
        __syncthreads();

        // ---- MFMA: wave wv owns c-tile [16wv,16wv+16); K=128 -> 4 steps ----
        {
            const int ca  = (wv << 4) + (lane & 15);
            const int rbq = lane & 15;
            const int rb  = (rbq < 8) ? rbq : 8;
            const int p   = lane >> 4;
            #pragma unroll
            for (int kk = 0; kk < 4; ++kk) {
                const int n8  = kk*32 + p*8;
                const int sl0 = ((n8 >> 2)     ^ (ca & 7));
                const int sl1 = (((n8 >> 2)+1) ^ (ca & 7));
                const float4 f0 = *(const float4*)&xlds[cur][ca*TA + sl0*4];
                const float4 f1 = *(const float4*)&xlds[cur][ca*TA + sl1*4];
                union { unsigned u[4]; bf16x8 v; } ua;
                ua.u[0] = bfpack(f0.x, f0.y);
                ua.u[1] = bfpack(f0.z, f0.w);
                ua.u[2] = bfpack(f1.x, f1.y);
                ua.u[3] = bfpack(f1.z, f1.w);
                const int slb = ((n8 >> 3) ^ (rb & 7));
                const bf16x8 bfr = *(const bf16x8*)&et[rb*TA + slb*8];
                accU = __builtin_amdgcn_mfma_f32_16x16x32_bf16(ua.v, bfr, accU, 0, 0, 0);
            }
        }
        asm volatile("s_waitcnt vmcnt(0)" ::: "memory");
        __syncthreads();
        cur ^= 1;
    }

    // ---- write U^T partials: D col = lane&15 = s, row = (lane>>4)*4+reg ----
    {
        const size_t base = ((size_t)(b*BPA + blk) * SS) * CC;
        if ((lane & 15) < SS) {
            const int s  = lane & 15;
            const int c0 = (wv << 4) + ((lane >> 4) << 2);
            #pragma unroll
            for (int r = 0; r < 4; ++r)
                U_part[base + s*CC + c0 + r] = accU[r];
        }
    }
    // ---- accS block reduce (tid<128 hold values); reuse red ----
    if (tid < TA) {
        #pragma unroll
        for (int s = 0; s < SS; ++s) red[s*TA + tid] = accS[s];
    }
    __syncthreads();
    {
        const int s = tid >> 5, j = tid & 31;
        float v = 0.f;
        #pragma unroll
        for (int k = 0; k < 4; ++k) v += red[s*TA + j*4 + k];
        v += __shfl_xor(v, 1); v += __shfl_xor(v, 2); v += __shfl_xor(v, 4);
        v += __shfl_xor(v, 8); v += __shfl_xor(v, 16);
        if (j == 0) sume_part[(size_t)(b*BPA + blk)*SS + s] = v;
    }
    #undef STAGE
}

// ---------------------------------------------------------------------------
// Kernel R: parallel reduce of partials -> upd[b,s,c] = U/L directly.
// ---------------------------------------------------------------------------
__global__ __launch_bounds__(256) void k_reduce2(
    const float* __restrict__ U_part, const float* __restrict__ sume_part,
    float* __restrict__ upd_g, int bpb)
{
    __shared__ float part[4][64];
    __shared__ float lbuf[256];
    __shared__ float Lsh;
    const int tid = threadIdx.x;
    const int b = blockIdx.x >> 3, s = blockIdx.x & 7;
    const int c = tid & 63, kc = tid >> 6;
    const int cnt = bpb >> 2;

    float lv = 0.f;
    for (int k = tid; k < bpb; k += 256)
        lv += sume_part[(size_t)(b*bpb + k)*SS + s];
    lbuf[tid] = lv;

    float acc[8];
    #pragma unroll
    for (int j = 0; j < 8; ++j) acc[j] = 0.f;
    const float* base = U_part + ((size_t)(b*bpb + kc*cnt)*SS + s)*CC + c;
    for (int k = 0; k < cnt; k += 8) {
        #pragma unroll
        for (int j = 0; j < 8; ++j)
            acc[j] += base[(size_t)(k + j) * SS * CC];
    }
    part[kc][c] = ((acc[0]+acc[1]) + (acc[2]+acc[3]))
                + ((acc[4]+acc[5]) + (acc[6]+acc[7]));
    __syncthreads();

    if (tid < 128) lbuf[tid] += lbuf[tid + 128];
    __syncthreads();
    if (tid < 64) {
        float v = lbuf[tid] + lbuf[tid + 64];
        v += __shfl_xor(v, 1); v += __shfl_xor(v, 2); v += __shfl_xor(v, 4);
        v += __shfl_xor(v, 8); v += __shfl_xor(v, 16); v += __shfl_xor(v, 32);
        if (tid == 0) Lsh = v;
    }
    __syncthreads();

    if (tid < 64) {
        float u = part[0][c] + part[1][c] + part[2][c] + part[3][c];
        upd_g[((size_t)b*SS + s)*CC + c] = u / Lsh;
    }
}

// ---------------------------------------------------------------------------
// Kernel B: slot pipeline. 4 blocks (one per batch), 256 threads.
// ---------------------------------------------------------------------------
__global__ __launch_bounds__(256) void k_slots_small(
    const float* __restrict__ upd_g,
    const float* __restrict__ spw, const float* __restrict__ spb,
    const float* __restrict__ lng, const float* __restrict__ lnb,
    const float* __restrict__ ipw, const float* __restrict__ ipb,
    const float* __restrict__ opw, const float* __restrict__ opb,
    const float* __restrict__ M, const float* __restrict__ g0v,
    const float* __restrict__ hv, const float* __restrict__ h0,
    float* __restrict__ st_out, float* __restrict__ g_out, float* __restrict__ h_out)
{
    __shared__ float upd[SS*CC];
    __shared__ float st [SS*CC];
    __shared__ float snb[SS*CC];
    __shared__ float qkv[SS*3*CC];
    __shared__ float ot [SS*CC];

    const int tid  = threadIdx.x;
    const int b    = blockIdx.x;
    const int c    = tid & 63;
    const int quad = tid >> 6;
    const int r0 = quad*2, r1 = r0 + 1;
    float wreg[CC];

    #pragma unroll
    for (int i = 0; i < 16; ++i)
        *(float4*)&wreg[i*4] = *(const float4*)(spw + c*CC + i*4);
    upd[r0*CC + c] = upd_g[(b*SS + r0)*CC + c];
    upd[r1*CC + c] = upd_g[(b*SS + r1)*CC + c];
    __syncthreads();

    // P1: slot_proj
    {
        const float bias = spb[c];
        float a0 = bias, a1 = bias;
        #pragma unroll
        for (int i = 0; i < 16; ++i) {
            float4 u0 = *(const float4*)&upd[r0*CC + i*4];
            float4 u1 = *(const float4*)&upd[r1*CC + i*4];
            a0 += u0.x*wreg[i*4+0] + u0.y*wreg[i*4+1] + u0.z*wreg[i*4+2] + u0.w*wreg[i*4+3];
            a1 += u1.x*wreg[i*4+0] + u1.y*wreg[i*4+1] + u1.z*wreg[i*4+2] + u1.w*wreg[i*4+3];
        }
        st[r0*CC + c] = a0;
        st[r1*CC + c] = a1;
    }
    __syncthreads();

    // P2: LayerNorm (32 threads per row)
    {
        const int row = tid >> 5, l = tid & 31;
        float v0 = st[row*CC + l], v1 = st[row*CC + l + 32];
        float sum = v0 + v1;
        sum += __shfl_xor(sum, 1); sum += __shfl_xor(sum, 2); sum += __shfl_xor(sum, 4);
        sum += __shfl_xor(sum, 8); sum += __shfl_xor(sum, 16);
        const float mu = sum * (1.f/64.f);
        const float d0 = v0 - mu, d1 = v1 - mu;
        float vs = d0*d0 + d1*d1;
        vs += __shfl_xor(vs, 1); vs += __shfl_xor(vs, 2); vs += __shfl_xor(vs, 4);
        vs += __shfl_xor(vs, 8); vs += __shfl_xor(vs, 16);
        const float rstd = rsqrtf(vs * (1.f/64.f) + 1e-5f);
        snb[row*CC + l]      = d0 * rstd * lng[l]      + lnb[l];
        snb[row*CC + l + 32] = d1 * rstd * lng[l + 32] + lnb[l + 32];
    }
    __syncthreads();

    // P3: qkv
    for (int m = 0; m < 3; ++m) {
        #pragma unroll
        for (int i = 0; i < 16; ++i)
            *(float4*)&wreg[i*4] = *(const float4*)(ipw + (size_t)(m*CC + c)*CC + i*4);
        const float bias = ipb[m*CC + c];
        float a0 = bias, a1 = bias;
        #pragma unroll
        for (int i = 0; i < 16; ++i) {
            float4 u0 = *(const float4*)&snb[r0*CC + i*4];
            float4 u1 = *(const float4*)&snb[r1*CC + i*4];
            a0 += u0.x*wreg[i*4+0] + u0.y*wreg[i*4+1] + u0.z*wreg[i*4+2] + u0.w*wreg[i*4+3];
            a1 += u1.x*wreg[i*4+0] + u1.y*wreg[i*4+1] + u1.z*wreg[i*4+2] + u1.w*wreg[i*4+3];
        }
        qkv[r0*3*CC + m*CC + c] = a0;
        qkv[r1*3*CC + m*CC + c] = a1;
    }
    __syncthreads();

    // P4: MHSA, 32 threads = (h,q)
    if (tid < NH_*SS) {
        const int h = tid >> 3, q = tid & 7;
        float qreg[HD_];
        #pragma unroll
        for (int i = 0; i < 4; ++i)
            *(float4*)&qreg[i*4] = *(const float4*)&qkv[q*3*CC + h*HD_ + i*4];
        float srow[SS];
        float mx = -1e30f;
        #pragma unroll
        for (int k = 0; k < SS; ++k) {
            float acc = 0.f;
            #pragma unroll
            for (int d = 0; d < HD_; ++d)
                acc += qreg[d] * qkv[k*3*CC + CC + h*HD_ + d];
            srow[k] = acc * 0.25f;
            mx = fmaxf(mx, srow[k]);
        }
        float l = 0.f;
        #pragma unroll
        for (int k = 0; k < SS; ++k) { srow[k] = __expf(srow[k] - mx); l += srow[k]; }
        const float inv = 1.f / l;
        float oreg[HD_];
        #pragma unroll
        for (int d = 0; d < HD_; ++d) oreg[d] = 0.f;
        #pragma unroll
        for (int k = 0; k < SS; ++k) {
            #pragma unroll
            for (int d = 0; d < HD_; ++d)
                oreg[d] += srow[k] * qkv[k*3*CC + 2*CC + h*HD_ + d];
        }
        #pragma unroll
        for (int d = 0; d < HD_; ++d)
            ot[q*CC + h*HD_ + d] = oreg[d] * inv;
    }
    __syncthreads();

    // P5: out_proj + residual
    #pragma unroll
    for (int i = 0; i < 16; ++i)
        *(float4*)&wreg[i*4] = *(const float4*)(opw + c*CC + i*4);
    {
        const float bias = opb[c];
        float a0 = bias, a1 = bias;
        #pragma unroll
        for (int i = 0; i < 16; ++i) {
            float4 u0 = *(const float4*)&ot[r0*CC + i*4];
            float4 u1 = *(const float4*)&ot[r1*CC + i*4];
            a0 += u0.x*wreg[i*4+0] + u0.y*wreg[i*4+1] + u0.z*wreg[i*4+2] + u0.w*wreg[i*4+3];
            a1 += u1.x*wreg[i*4+0] + u1.y*wreg[i*4+1] + u1.z*wreg[i*4+2] + u1.w*wreg[i*4+3];
        }
        st[r0*CC + c] += a0;
        st[r1*CC + c] += a1;
    }
    __syncthreads();

    // P6: g = st @ M + g0 ; emit st ; h = st.hv + h0
    #pragma unroll 8
    for (int cp = 0; cp < CC; ++cp) wreg[cp] = M[cp*CC + c];
    {
        const float g0 = g0v[c];
        float a0 = g0, a1 = g0;
        #pragma unroll
        for (int i = 0; i < 16; ++i) {
            float4 s0 = *(const float4*)&st[r0*CC + i*4];
            float4 s1 = *(const float4*)&st[r1*CC + i*4];
            a0 += s0.x*wreg[i*4+0] + s0.y*wreg[i*4+1] + s0.z*wreg[i*4+2] + s0.w*wreg[i*4+3];
            a1 += s1.x*wreg[i*4+0] + s1.y*wreg[i*4+1] + s1.z*wreg[i*4+2] + s1.w*wreg[i*4+3];
        }
        g_out[(b*SS + r0)*CC + c] = a0;
        g_out[(b*SS + r1)*CC + c] = a1;
        st_out[(b*SS + r0)*CC + c] = st[r0*CC + c];
        st_out[(b*SS + r1)*CC + c] = st[r1*CC + c];
    }
    {
        const int row = tid >> 5, l = tid & 31;
        float pv = st[row*CC + l]*hv[l] + st[row*CC + l + 32]*hv[l + 32];
        pv += __shfl_xor(pv, 1); pv += __shfl_xor(pv, 2); pv += __shfl_xor(pv, 4);
        pv += __shfl_xor(pv, 8); pv += __shfl_xor(pv, 16);
        if (l == 0) h_out[b*SS + row] = pv + *h0;
    }
}

// ---------------------------------------------------------------------------
// Kernel C: stage-3 fused pass (R9's proven one-pass fp32 shape) + NT stores.
// ---------------------------------------------------------------------------
__global__ __launch_bounds__(256) void k_feat(
    const float* __restrict__ x,
    const float* __restrict__ st_g, const float* __restrict__ g_g,
    const float* __restrict__ h_g,
    float* __restrict__ out)
{
    __shared__ float stS[SS*CC];
    __shared__ float gS [SS*CC];
    __shared__ float hS [SS];

    const int tid = threadIdx.x;
    const int b  = blockIdx.x >> 9;
    const int n  = ((blockIdx.x & 511) << 8) + tid;

    for (int i = tid; i < SS*CC; i += 256) {
        stS[i] = st_g[b*SS*CC + i];
        gS[i]  = g_g [b*SS*CC + i];
    }
    if (tid < SS) hS[tid] = h_g[b*SS + tid];
    __syncthreads();

    const float* xb = x + (size_t)b * CC * NN + n;
    float xc[CC];
    #pragma unroll
    for (int c = 0; c < CC; ++c) xc[c] = xb[(size_t)c * NN];

    float a[SS];
    #pragma unroll
    for (int s = 0; s < SS; ++s) a[s] = hS[s];
    #pragma unroll
    for (int c4 = 0; c4 < CC/4; ++c4) {
        #pragma unroll
        for (int s = 0; s < SS; ++s) {
            float4 g4 = *(const float4*)(&gS[s*CC + c4*4]);
            a[s] += g4.x*xc[c4*4+0] + g4.y*xc[c4*4+1]
                  + g4.z*xc[c4*4+2] + g4.w*xc[c4*4+3];
        }
    }

    float m = a[0];
    #pragma unroll
    for (int s = 1; s < SS; ++s) m = fmaxf(m, a[s]);
    float l = 0.f;
    #pragma unroll
    for (int s = 0; s < SS; ++s) { a[s] = __expf(a[s] - m); l += a[s]; }
    const float inv = 1.f / l;

    float* ob = out + (size_t)b * CC * NN + n;
    #pragma unroll
    for (int c4 = 0; c4 < CC/4; ++c4) {
        float o0 = 0.f, o1 = 0.f, o2 = 0.f, o3 = 0.f;
        #pragma unroll
        for (int s = 0; s < SS; ++s) {
            float4 s4 = *(const float4*)(&stS[s*CC + c4*4]);
            o0 += s4.x * a[s]; o1 += s4.y * a[s];
            o2 += s4.z * a[s]; o3 += s4.w * a[s];
        }
        __builtin_nontemporal_store(o0 * inv + xc[c4*4+0], ob + (size_t)(c4*4+0) * NN);
        __builtin_nontemporal_store(o1 * inv + xc[c4*4+1], ob + (size_t)(c4*4+1) * NN);
        __builtin_nontemporal_store(o2 * inv + xc[c4*4+2], ob + (size_t)(c4*4+2) * NN);
        __builtin_nontemporal_store(o3 * inv + xc[c4*4+3], ob + (size_t)(c4*4+3) * NN);
    }
}

// ---------------------------------------------------------------------------
extern "C" void kernel_launch(void* const* d_in, const int* in_sizes, int n_in,
                              void* d_out, int out_size, void* d_ws, size_t ws_size,
                              hipStream_t stream) {
    const float* x         = (const float*)d_in[0];
    const float* slot_init = (const float*)d_in[1];
    const float* spw       = (const float*)d_in[2];
    const float* spb       = (const float*)d_in[3];
    const float* lng       = (const float*)d_in[4];
    const float* lnb       = (const float*)d_in[5];
    const float* ipw       = (const float*)d_in[6];
    const float* ipb       = (const float*)d_in[7];
    const float* opw       = (const float*)d_in[8];
    const float* opb       = (const float*)d_in[9];
    const float* fw        = (const float*)d_in[10];
    const float* fb        = (const float*)d_in[11];
    const float* s2fw      = (const float*)d_in[12];
    const float* s2fb      = (const float*)d_in[13];
    float* out = (float*)d_out;

    float* w         = (float*)d_ws;
    float* U_part    = w;                                  // 4*128*8*64 = 262144
    float* sume_part = U_part + (size_t)BB*BPA*SS*CC;      // 4096
    float* upd_g     = sume_part + (size_t)BB*BPA*SS;      // 2048
    float* Mm        = upd_g + 2048;                       // 4096
    float* g0v       = Mm + 4096;                          // 64
    float* hv        = g0v + 64;                           // 64
    float* h0        = hv + 64;                            // 64 (1 used)
    float* snT_ws    = h0 + 64;                            // 512 (1024 reserved)
    float* st_out    = snT_ws + 1024;                      // 2048
    float* g_out     = st_out + 2048;                      // 2048
    float* h_out     = g_out + 2048;                       // 32

    k_precomp<<<18, 256, 0, stream>>>(slot_init, s2fw, s2fb, fw, fb,
                                      Mm, g0v, hv, h0, snT_ws);
    k_slots_attn<<<BB * BPA, 256, 0, stream>>>(x, snT_ws, U_part, sume_part);
    k_reduce2<<<BB * SS, 256, 0, stream>>>(U_part, sume_part, upd_g, BPA);
    k_slots_small<<<BB, 256, 0, stream>>>(upd_g, spw, spb, lng, lnb,
                                          ipw, ipb, opw, opb, Mm, g0v, hv, h0,
                                          st_out, g_out, h_out);
    k_feat<<<BB * (NN/256), 256, 0, stream>>>(x, st_out, g_out, h_out, out);
}